// Round 5
// baseline (332.384 us; speedup 1.0000x reference)
//
#include <hip/hip_runtime.h>

#define STEPS 32768
#define DIO 63
#define HSZ 256
#define NL 6
#define BM 32
#define THREADS 256

// fragment-ordered weights in d_ws (A-role fragments; lane l = feature row l&15, k-slice (l>>4)*8)
#define NBGF  (NL * 3 * 16 * 8 * 64 * 8)   // [l][g][nb=16][kk=8][lane][e], bf16, pre-scaled by log2e factors
#define NBIAS (NL * 768)                    // fused (b_ih+b_hh)*scale, f32, [l][g][256]
#define NBINF (16 * 2 * 64 * 8)             // W_in  [nb][kk][lane][e], K padded 63->64
#define NBFCF (4 * 8 * 64 * 8)              // W_fc  [nb][kk][lane][e]

typedef __bf16 bf16_8 __attribute__((ext_vector_type(8)));
typedef __bf16 bf16_4 __attribute__((ext_vector_type(4)));
typedef float f32x4 __attribute__((ext_vector_type(4)));

#define LOG2E  1.4426950408889634f
#define LOG2E2 2.8853900817779268f

__device__ __forceinline__ unsigned short f2bf(float f) {
    unsigned int u = __float_as_uint(f);
    u = u + 0x7fffu + ((u >> 16) & 1u);   // RNE
    return (unsigned short)(u >> 16);
}

// ---- weight prep: fp32 -> bf16, MFMA A-fragment order, log2e pre-scaling ----
__global__ void prep_kernel(const float* __restrict__ W_in,
                            const float* __restrict__ W_ih,
                            const float* __restrict__ b_ih,
                            const float* __restrict__ b_hh,
                            const float* __restrict__ W_fc,
                            unsigned short* __restrict__ Bg,
                            float* __restrict__ bias,
                            unsigned short* __restrict__ Bin,
                            unsigned short* __restrict__ Bfc) {
    int idx = blockIdx.x * 256 + threadIdx.x;
    if (idx < NBGF) {
        int e    = idx & 7;
        int lane = (idx >> 3) & 63;
        int kk   = (idx >> 9) & 7;
        int nb   = (idx >> 12) & 15;
        int lg   = idx >> 16;          // 0..17
        int l = lg / 3, g = lg % 3;
        int f = nb * 16 + (lane & 15);
        int k = kk * 32 + (lane >> 4) * 8 + e;
        int r = f + (g == 0 ? 0 : (g == 1 ? 512 : 768));   // torch gate order i,f,g,o; f dead
        float sc = (g == 1) ? LOG2E2 : LOG2E;              // exp2-ready gates
        Bg[idx] = f2bf(W_ih[((size_t)l * 1024 + r) * HSZ + k] * sc);
        return;
    }
    idx -= NBGF;
    if (idx < NBIAS) {
        int j = idx % 768, l = idx / 768;
        int g = j >> 8;
        int r = (j < 256) ? j : j + 256;
        float sc = (g == 1) ? LOG2E2 : LOG2E;
        bias[idx] = (b_ih[l * 1024 + r] + b_hh[l * 1024 + r]) * sc;
        return;
    }
    idx -= NBIAS;
    if (idx < NBINF) {
        int e = idx & 7, lane = (idx >> 3) & 63, kk = (idx >> 9) & 1, nb = idx >> 10;
        int f = nb * 16 + (lane & 15);
        int k = kk * 32 + (lane >> 4) * 8 + e;
        Bin[idx] = (k < DIO) ? f2bf(W_in[f * DIO + k]) : (unsigned short)0;
        return;
    }
    idx -= NBINF;
    if (idx < NBFCF) {
        int e = idx & 7, lane = (idx >> 3) & 63, kk = (idx >> 9) & 7, nb = idx >> 12;
        int f = nb * 16 + (lane & 15);
        int k = kk * 32 + (lane >> 4) * 8 + e;
        Bfc[idx] = (f < DIO) ? f2bf(W_fc[f * HSZ + k]) : (unsigned short)0;
    }
}

// ---- fused MLP-ized LSTM, operand-swapped (gates^T = W * h^T) ----
// 4 waves/block, 32 steps/block, 1024 blocks -> 4 barrier-groups/CU.
// h double-buffered in LDS [buf][kk=8][lq=4][s=32][e=8] -> 1 barrier/layer.
__global__ __launch_bounds__(THREADS, 4) void rnn_fused(
    const float* __restrict__ inp, const float* __restrict__ b_in,
    const float* __restrict__ b_fc,
    const unsigned short* __restrict__ Bg, const float* __restrict__ bias,
    const unsigned short* __restrict__ Bin, const unsigned short* __restrict__ Bfc,
    float* __restrict__ out) {
    __shared__ __align__(16) unsigned short h_lds[2 * 8 * 4 * 32 * 8];   // 16KB (2 bufs)
    __shared__ __align__(16) unsigned short in_lds[2 * 4 * 32 * 8];      //  4KB

    const int tid = threadIdx.x;
    const int lane = tid & 63;
    const int l15 = lane & 15;
    const int lq = lane >> 4;
    const int wid = tid >> 6;          // 0..3; wave owns features wid*64..+63, all 32 steps
    const int row0 = blockIdx.x * BM;

    // one LDS read-base for ALL B-fragment reads; one write-base for epilogues
    const int rdBase = lq * 512 + l15 * 16;
    const int wrBase = wid * 4096 + (lq >> 1) * 512 + l15 * 16 + (lq & 1) * 8;

    // ---- stage input tile (32 x 63 fp32 -> bf16, K padded to 64), layout [kk][lq][s][e] ----
    for (int idx = tid; idx < BM * 64; idx += THREADS) {
        int s = idx >> 6, k = idx & 63;
        float v = (k < DIO) ? inp[(size_t)(row0 + s) * DIO + k] : 0.f;
        int off = (k >> 5) * 2048 + ((k >> 3) & 3) * 512 + s * 16 + (k & 7) * 2;
        *(unsigned short*)((char*)in_lds + off) = f2bf(v);
    }
    __syncthreads();

    // ---- input GEMM: x^T = W_in * inp^T + b_in -> h buf0 ----
    {
        f32x4 acc[4][2];
#pragma unroll
        for (int m = 0; m < 4; ++m) {
            f32x4 b4 = *(const f32x4*)(b_in + wid * 64 + m * 16 + lq * 4);
#pragma unroll
            for (int n = 0; n < 2; ++n) acc[m][n] = b4;
        }
        const bf16_8* __restrict__ pA = (const bf16_8*)Bin;
#pragma unroll
        for (int kk = 0; kk < 2; ++kk) {
            bf16_8 a[4], b[2];
#pragma unroll
            for (int m = 0; m < 4; ++m) a[m] = pA[((wid * 4 + m) * 2 + kk) * 64 + lane];
#pragma unroll
            for (int n = 0; n < 2; ++n)
                b[n] = *(const bf16_8*)((const char*)in_lds + rdBase + kk * 2048 + n * 256);
#pragma unroll
            for (int m = 0; m < 4; ++m)
#pragma unroll
                for (int n = 0; n < 2; ++n)
                    acc[m][n] = __builtin_amdgcn_mfma_f32_16x16x32_bf16(a[m], b[n], acc[m][n], 0, 0, 0);
        }
#pragma unroll
        for (int m = 0; m < 4; ++m)
#pragma unroll
            for (int n = 0; n < 2; ++n) {
                bf16_4 hv;
#pragma unroll
                for (int r = 0; r < 4; ++r) hv[r] = (__bf16)acc[m][n][r];
                *(bf16_4*)((char*)h_lds + wrBase + (m >> 1) * 2048 + (m & 1) * 1024 + n * 256) = hv;
            }
    }
    __syncthreads();

    // ---- 6 layers x 3 gates (i,g,o; f-gate dead since c_prev==0) ----
    for (int l = 0; l < NL; ++l) {
        const char* cur = (const char*)h_lds + (l & 1) * 8192;
        char* nxt = (char*)h_lds + ((l + 1) & 1) * 8192;
        f32x4 tt[4][2];
#pragma unroll
        for (int g = 0; g < 3; ++g) {
            const bf16_8* __restrict__ pA = (const bf16_8*)(Bg + ((size_t)(l * 3 + g) << 16));
            const float* __restrict__ bg = bias + (l * 3 + g) * 256;
            f32x4 acc[4][2];
#pragma unroll
            for (int m = 0; m < 4; ++m) {
                f32x4 b4 = *(const f32x4*)(bg + wid * 64 + m * 16 + lq * 4);
#pragma unroll
                for (int n = 0; n < 2; ++n) acc[m][n] = b4;
            }
#pragma unroll
            for (int kk = 0; kk < 8; ++kk) {
                bf16_8 a[4], b[2];
#pragma unroll
                for (int m = 0; m < 4; ++m) a[m] = pA[((wid * 4 + m) * 8 + kk) * 64 + lane];
#pragma unroll
                for (int n = 0; n < 2; ++n)
                    b[n] = *(const bf16_8*)(cur + rdBase + kk * 2048 + n * 256);
#pragma unroll
                for (int m = 0; m < 4; ++m)
#pragma unroll
                    for (int n = 0; n < 2; ++n)
                        acc[m][n] = __builtin_amdgcn_mfma_f32_16x16x32_bf16(a[m], b[n], acc[m][n], 0, 0, 0);
            }
            // g0: tt = e^i (gates pre-scaled by log2e)
            // g1: tt = c = ei(eg-1)/((1+ei)(1+eg))   [sig(i)*tanh(g)]
            // g2: h  = sig(o)*tanh(c) fused: (eo*c*tn(z)) * rcp((1+eo)*td(z)), z=c^2
            if (g < 2) {
#pragma unroll
                for (int m = 0; m < 4; ++m)
#pragma unroll
                    for (int n = 0; n < 2; ++n)
#pragma unroll
                        for (int r = 0; r < 4; ++r) {
                            float v = acc[m][n][r];
                            if (g == 0) {
                                tt[m][n][r] = __builtin_amdgcn_exp2f(fminf(v, 34.f));
                            } else {
                                float eg = __builtin_amdgcn_exp2f(fminf(v, 60.f));
                                float ei = tt[m][n][r];
                                tt[m][n][r] = ei * (eg - 1.f) *
                                              __builtin_amdgcn_rcpf((1.f + ei) * (1.f + eg));
                            }
                        }
            } else {
#pragma unroll
                for (int m = 0; m < 4; ++m)
#pragma unroll
                    for (int n = 0; n < 2; ++n) {
                        bf16_4 hv;
#pragma unroll
                        for (int r = 0; r < 4; ++r) {
                            float eo = __builtin_amdgcn_exp2f(fminf(acc[m][n][r], 34.f));
                            float c = tt[m][n][r];
                            float z = c * c;
                            float tn = fmaf(z + 105.f, z, 945.f);
                            float td = fmaf(fmaf(15.f, z, 420.f), z, 945.f);
                            hv[r] = (__bf16)(eo * c * tn *
                                             __builtin_amdgcn_rcpf((1.f + eo) * td));
                        }
                        *(bf16_4*)(nxt + wrBase + (m >> 1) * 2048 + (m & 1) * 1024 + n * 256) = hv;
                    }
            }
        }
        __syncthreads();   // writes to nxt visible; everyone done reading cur
    }

    // ---- final GEMM: out^T = W_fc * h^T + b_fc (reads buf0 = buf[NL&1]) ----
    {
        const char* cur = (const char*)h_lds;   // NL even -> buf0
        f32x4 o4[2];
#pragma unroll
        for (int n = 0; n < 2; ++n) o4[n] = (f32x4){0.f, 0.f, 0.f, 0.f};
        const bf16_8* __restrict__ pA = (const bf16_8*)Bfc;
#pragma unroll
        for (int kk = 0; kk < 8; ++kk) {
            bf16_8 a = pA[(wid * 8 + kk) * 64 + lane];
#pragma unroll
            for (int n = 0; n < 2; ++n) {
                bf16_8 b = *(const bf16_8*)(cur + rdBase + kk * 2048 + n * 256);
                o4[n] = __builtin_amdgcn_mfma_f32_16x16x32_bf16(a, b, o4[n], 0, 0, 0);
            }
        }
#pragma unroll
        for (int n = 0; n < 2; ++n) {
            int s = row0 + n * 16 + l15;
#pragma unroll
            for (int r = 0; r < 4; ++r) {
                int f = wid * 16 + lq * 4 + r;
                if (f < DIO) out[(size_t)s * DIO + f] = o4[n][r] + b_fc[f];
            }
        }
    }
}

extern "C" void kernel_launch(void* const* d_in, const int* in_sizes, int n_in,
                              void* d_out, int out_size, void* d_ws, size_t ws_size,
                              hipStream_t stream) {
    const float* inputs = (const float*)d_in[0];
    const float* W_in   = (const float*)d_in[1];
    const float* b_in   = (const float*)d_in[2];
    const float* W_ih   = (const float*)d_in[3];
    // d_in[4] = W_hh: unused (h_prev == 0 every step)
    const float* b_ih   = (const float*)d_in[5];
    const float* b_hh   = (const float*)d_in[6];
    const float* W_fc   = (const float*)d_in[7];
    const float* b_fc   = (const float*)d_in[8];

    unsigned short* Bg  = (unsigned short*)d_ws;
    float* bias         = (float*)((char*)d_ws + (size_t)NBGF * 2);
    unsigned short* Bin = (unsigned short*)((char*)bias + (size_t)NBIAS * 4);
    unsigned short* Bfc = Bin + NBINF;

    int total = NBGF + NBIAS + NBINF + NBFCF;
    prep_kernel<<<(total + 255) / 256, 256, 0, stream>>>(W_in, W_ih, b_ih, b_hh, W_fc,
                                                         Bg, bias, Bin, Bfc);
    rnn_fused<<<STEPS / BM, THREADS, 0, stream>>>(inputs, b_in, b_fc, Bg, bias, Bin, Bfc,
                                                  (float*)d_out);
}

// Round 6
// 248.580 us; speedup vs baseline: 1.3371x; 1.3371x over previous
//
#include <hip/hip_runtime.h>

#define STEPS 32768
#define DIO 63
#define HSZ 256
#define NL 6
#define BM 32
#define THREADS 256

// fragment-ordered weights in d_ws (A-role fragments; lane l = feature row l&15, k-slice (l>>4)*8)
#define NBGF  (NL * 3 * 16 * 8 * 64 * 8)   // [l][g][nb=16][kk=8][lane][e], bf16, pre-scaled by log2e factors
#define NBIAS (NL * 768)                    // fused (b_ih+b_hh)*scale, f32, [l][g][256]
#define NBINF (16 * 2 * 64 * 8)             // W_in  [nb][kk][lane][e], K padded 63->64
#define NBFCF (4 * 8 * 64 * 8)              // W_fc  [nb][kk][lane][e]

typedef __bf16 bf16_8 __attribute__((ext_vector_type(8)));
typedef __bf16 bf16_4 __attribute__((ext_vector_type(4)));
typedef float f32x4 __attribute__((ext_vector_type(4)));

#define LOG2E  1.4426950408889634f
#define LOG2E2 2.8853900817779268f

__device__ __forceinline__ unsigned short f2bf(float f) {
    unsigned int u = __float_as_uint(f);
    u = u + 0x7fffu + ((u >> 16) & 1u);   // RNE
    return (unsigned short)(u >> 16);
}

// ---- weight prep: fp32 -> bf16, MFMA A-fragment order, log2e pre-scaling ----
__global__ void prep_kernel(const float* __restrict__ W_in,
                            const float* __restrict__ W_ih,
                            const float* __restrict__ b_ih,
                            const float* __restrict__ b_hh,
                            const float* __restrict__ W_fc,
                            unsigned short* __restrict__ Bg,
                            float* __restrict__ bias,
                            unsigned short* __restrict__ Bin,
                            unsigned short* __restrict__ Bfc) {
    int idx = blockIdx.x * 256 + threadIdx.x;
    if (idx < NBGF) {
        int e    = idx & 7;
        int lane = (idx >> 3) & 63;
        int kk   = (idx >> 9) & 7;
        int nb   = (idx >> 12) & 15;
        int lg   = idx >> 16;          // 0..17
        int l = lg / 3, g = lg % 3;
        int f = nb * 16 + (lane & 15);
        int k = kk * 32 + (lane >> 4) * 8 + e;
        int r = f + (g == 0 ? 0 : (g == 1 ? 512 : 768));   // torch gate order i,f,g,o; f dead
        float sc = (g == 1) ? LOG2E2 : LOG2E;              // exp2-ready gates
        Bg[idx] = f2bf(W_ih[((size_t)l * 1024 + r) * HSZ + k] * sc);
        return;
    }
    idx -= NBGF;
    if (idx < NBIAS) {
        int j = idx % 768, l = idx / 768;
        int g = j >> 8;
        int r = (j < 256) ? j : j + 256;
        float sc = (g == 1) ? LOG2E2 : LOG2E;
        bias[idx] = (b_ih[l * 1024 + r] + b_hh[l * 1024 + r]) * sc;
        return;
    }
    idx -= NBIAS;
    if (idx < NBINF) {
        int e = idx & 7, lane = (idx >> 3) & 63, kk = (idx >> 9) & 1, nb = idx >> 10;
        int f = nb * 16 + (lane & 15);
        int k = kk * 32 + (lane >> 4) * 8 + e;
        Bin[idx] = (k < DIO) ? f2bf(W_in[f * DIO + k]) : (unsigned short)0;
        return;
    }
    idx -= NBINF;
    if (idx < NBFCF) {
        int e = idx & 7, lane = (idx >> 3) & 63, kk = (idx >> 9) & 7, nb = idx >> 12;
        int f = nb * 16 + (lane & 15);
        int k = kk * 32 + (lane >> 4) * 8 + e;
        Bfc[idx] = (f < DIO) ? f2bf(W_fc[f * HSZ + k]) : (unsigned short)0;
    }
}

// ---- fused MLP-ized LSTM, operand-swapped (gates^T = W * h^T) ----
// 4 waves/block, 32 steps/block, 1024 blocks.
// __launch_bounds__ 2nd arg measured law (R1/R2/R5): VGPR cap = 256/arg,
// independent of block size -> arg=2 gives 128-VGPR cap; demand ~100 fits,
// no spills; at <=128 VGPR occupancy = 16 waves/CU = 4 blocks/CU = 4
// independent barrier groups (the concurrency this config targets).
// h double-buffered in LDS [buf][kk=8][lq=4][s=32][e=8] -> 1 barrier/layer.
__global__ __launch_bounds__(THREADS, 2) void rnn_fused(
    const float* __restrict__ inp, const float* __restrict__ b_in,
    const float* __restrict__ b_fc,
    const unsigned short* __restrict__ Bg, const float* __restrict__ bias,
    const unsigned short* __restrict__ Bin, const unsigned short* __restrict__ Bfc,
    float* __restrict__ out) {
    __shared__ __align__(16) unsigned short h_lds[2 * 8 * 4 * 32 * 8];   // 16KB (2 bufs)
    __shared__ __align__(16) unsigned short in_lds[2 * 4 * 32 * 8];      //  4KB

    const int tid = threadIdx.x;
    const int lane = tid & 63;
    const int l15 = lane & 15;
    const int lq = lane >> 4;
    const int wid = tid >> 6;          // 0..3; wave owns features wid*64..+63, all 32 steps
    const int row0 = blockIdx.x * BM;

    // one LDS read-base for ALL B-fragment reads; one write-base for epilogues
    const int rdBase = lq * 512 + l15 * 16;
    const int wrBase = wid * 4096 + (lq >> 1) * 512 + l15 * 16 + (lq & 1) * 8;

    // ---- stage input tile (32 x 63 fp32 -> bf16, K padded to 64), layout [kk][lq][s][e] ----
    for (int idx = tid; idx < BM * 64; idx += THREADS) {
        int s = idx >> 6, k = idx & 63;
        float v = (k < DIO) ? inp[(size_t)(row0 + s) * DIO + k] : 0.f;
        int off = (k >> 5) * 2048 + ((k >> 3) & 3) * 512 + s * 16 + (k & 7) * 2;
        *(unsigned short*)((char*)in_lds + off) = f2bf(v);
    }
    __syncthreads();

    // ---- input GEMM: x^T = W_in * inp^T + b_in -> h buf0 ----
    {
        f32x4 acc[4][2];
#pragma unroll
        for (int m = 0; m < 4; ++m) {
            f32x4 b4 = *(const f32x4*)(b_in + wid * 64 + m * 16 + lq * 4);
#pragma unroll
            for (int n = 0; n < 2; ++n) acc[m][n] = b4;
        }
        const bf16_8* __restrict__ pA = (const bf16_8*)Bin;
#pragma unroll
        for (int kk = 0; kk < 2; ++kk) {
            bf16_8 a[4], b[2];
#pragma unroll
            for (int m = 0; m < 4; ++m) a[m] = pA[((wid * 4 + m) * 2 + kk) * 64 + lane];
#pragma unroll
            for (int n = 0; n < 2; ++n)
                b[n] = *(const bf16_8*)((const char*)in_lds + rdBase + kk * 2048 + n * 256);
#pragma unroll
            for (int m = 0; m < 4; ++m)
#pragma unroll
                for (int n = 0; n < 2; ++n)
                    acc[m][n] = __builtin_amdgcn_mfma_f32_16x16x32_bf16(a[m], b[n], acc[m][n], 0, 0, 0);
        }
#pragma unroll
        for (int m = 0; m < 4; ++m)
#pragma unroll
            for (int n = 0; n < 2; ++n) {
                bf16_4 hv;
#pragma unroll
                for (int r = 0; r < 4; ++r) hv[r] = (__bf16)acc[m][n][r];
                *(bf16_4*)((char*)h_lds + wrBase + (m >> 1) * 2048 + (m & 1) * 1024 + n * 256) = hv;
            }
    }
    __syncthreads();

    // ---- 6 layers x 3 gates (i,g,o; f-gate dead since c_prev==0) ----
    for (int l = 0; l < NL; ++l) {
        const char* cur = (const char*)h_lds + (l & 1) * 8192;
        char* nxt = (char*)h_lds + ((l + 1) & 1) * 8192;
        f32x4 tt[4][2];
#pragma unroll
        for (int g = 0; g < 3; ++g) {
            const bf16_8* __restrict__ pA = (const bf16_8*)(Bg + ((size_t)(l * 3 + g) << 16));
            const float* __restrict__ bg = bias + (l * 3 + g) * 256;
            f32x4 acc[4][2];
#pragma unroll
            for (int m = 0; m < 4; ++m) {
                f32x4 b4 = *(const f32x4*)(bg + wid * 64 + m * 16 + lq * 4);
#pragma unroll
                for (int n = 0; n < 2; ++n) acc[m][n] = b4;
            }
#pragma unroll
            for (int kk = 0; kk < 8; ++kk) {
                bf16_8 a[4], b[2];
#pragma unroll
                for (int m = 0; m < 4; ++m) a[m] = pA[((wid * 4 + m) * 8 + kk) * 64 + lane];
#pragma unroll
                for (int n = 0; n < 2; ++n)
                    b[n] = *(const bf16_8*)(cur + rdBase + kk * 2048 + n * 256);
#pragma unroll
                for (int m = 0; m < 4; ++m)
#pragma unroll
                    for (int n = 0; n < 2; ++n)
                        acc[m][n] = __builtin_amdgcn_mfma_f32_16x16x32_bf16(a[m], b[n], acc[m][n], 0, 0, 0);
            }
            // g0: tt = e^i (gates pre-scaled by log2e)
            // g1: tt = c = ei(eg-1)/((1+ei)(1+eg))   [sig(i)*tanh(g)]
            // g2: h  = sig(o)*tanh(c) fused: (eo*c*tn(z)) * rcp((1+eo)*td(z)), z=c^2
            if (g < 2) {
#pragma unroll
                for (int m = 0; m < 4; ++m)
#pragma unroll
                    for (int n = 0; n < 2; ++n)
#pragma unroll
                        for (int r = 0; r < 4; ++r) {
                            float v = acc[m][n][r];
                            if (g == 0) {
                                tt[m][n][r] = __builtin_amdgcn_exp2f(fminf(v, 34.f));
                            } else {
                                float eg = __builtin_amdgcn_exp2f(fminf(v, 60.f));
                                float ei = tt[m][n][r];
                                tt[m][n][r] = ei * (eg - 1.f) *
                                              __builtin_amdgcn_rcpf((1.f + ei) * (1.f + eg));
                            }
                        }
            } else {
#pragma unroll
                for (int m = 0; m < 4; ++m)
#pragma unroll
                    for (int n = 0; n < 2; ++n) {
                        bf16_4 hv;
#pragma unroll
                        for (int r = 0; r < 4; ++r) {
                            float eo = __builtin_amdgcn_exp2f(fminf(acc[m][n][r], 34.f));
                            float c = tt[m][n][r];
                            float z = c * c;
                            float tn = fmaf(z + 105.f, z, 945.f);
                            float td = fmaf(fmaf(15.f, z, 420.f), z, 945.f);
                            hv[r] = (__bf16)(eo * c * tn *
                                             __builtin_amdgcn_rcpf((1.f + eo) * td));
                        }
                        *(bf16_4*)(nxt + wrBase + (m >> 1) * 2048 + (m & 1) * 1024 + n * 256) = hv;
                    }
            }
        }
        __syncthreads();   // writes to nxt visible; everyone done reading cur
    }

    // ---- final GEMM: out^T = W_fc * h^T + b_fc (reads buf0 = buf[NL&1]) ----
    {
        const char* cur = (const char*)h_lds;   // NL even -> buf0
        f32x4 o4[2];
#pragma unroll
        for (int n = 0; n < 2; ++n) o4[n] = (f32x4){0.f, 0.f, 0.f, 0.f};
        const bf16_8* __restrict__ pA = (const bf16_8*)Bfc;
#pragma unroll
        for (int kk = 0; kk < 8; ++kk) {
            bf16_8 a = pA[(wid * 8 + kk) * 64 + lane];
#pragma unroll
            for (int n = 0; n < 2; ++n) {
                bf16_8 b = *(const bf16_8*)(cur + rdBase + kk * 2048 + n * 256);
                o4[n] = __builtin_amdgcn_mfma_f32_16x16x32_bf16(a, b, o4[n], 0, 0, 0);
            }
        }
#pragma unroll
        for (int n = 0; n < 2; ++n) {
            int s = row0 + n * 16 + l15;
#pragma unroll
            for (int r = 0; r < 4; ++r) {
                int f = wid * 16 + lq * 4 + r;
                if (f < DIO) out[(size_t)s * DIO + f] = o4[n][r] + b_fc[f];
            }
        }
    }
}

extern "C" void kernel_launch(void* const* d_in, const int* in_sizes, int n_in,
                              void* d_out, int out_size, void* d_ws, size_t ws_size,
                              hipStream_t stream) {
    const float* inputs = (const float*)d_in[0];
    const float* W_in   = (const float*)d_in[1];
    const float* b_in   = (const float*)d_in[2];
    const float* W_ih   = (const float*)d_in[3];
    // d_in[4] = W_hh: unused (h_prev == 0 every step)
    const float* b_ih   = (const float*)d_in[5];
    const float* b_hh   = (const float*)d_in[6];
    const float* W_fc   = (const float*)d_in[7];
    const float* b_fc   = (const float*)d_in[8];

    unsigned short* Bg  = (unsigned short*)d_ws;
    float* bias         = (float*)((char*)d_ws + (size_t)NBGF * 2);
    unsigned short* Bin = (unsigned short*)((char*)bias + (size_t)NBIAS * 4);
    unsigned short* Bfc = Bin + NBINF;

    int total = NBGF + NBIAS + NBINF + NBFCF;
    prep_kernel<<<(total + 255) / 256, 256, 0, stream>>>(W_in, W_ih, b_ih, b_hh, W_fc,
                                                         Bg, bias, Bin, Bfc);
    rnn_fused<<<STEPS / BM, THREADS, 0, stream>>>(inputs, b_in, b_fc, Bg, bias, Bin, Bfc,
                                                  (float*)d_out);
}

// Round 7
// 174.182 us; speedup vs baseline: 1.9083x; 1.4271x over previous
//
#include <hip/hip_runtime.h>

#define STEPS 32768
#define DIO 63
#define HSZ 256
#define NL 6
#define BM 64
#define THREADS 512

// B-operand fragment-ordered weights in d_ws:
// frag (nb,kk) = 1KB: lane l holds W[col=nb*16+(l&15)][k=kk*32+(l>>4)*8 .. +8]
#define NBGF  (NL * 3 * 16 * 8 * 64 * 8)   // [l][g][nb][kk][lane][e], bf16, log2e-prescaled
#define NBIAS (NL * 768)                    // fused (b_ih+b_hh)*scale, f32
#define NBINF (16 * 2 * 64 * 8)             // W_in  [nb][kk][lane][e], K 63->64
#define NBFCF (4 * 8 * 64 * 8)              // W_fc  [nb][kk][lane][e]

typedef __bf16 bf16_8 __attribute__((ext_vector_type(8)));
typedef float f32x4 __attribute__((ext_vector_type(4)));

#define LOG2E  1.4426950408889634f
#define LOG2E2 2.8853900817779268f

__device__ __forceinline__ unsigned short f2bf(float f) {
    unsigned int u = __float_as_uint(f);
    u = u + 0x7fffu + ((u >> 16) & 1u);   // RNE
    return (unsigned short)(u >> 16);
}

__global__ void prep_kernel(const float* __restrict__ W_in,
                            const float* __restrict__ W_ih,
                            const float* __restrict__ b_ih,
                            const float* __restrict__ b_hh,
                            const float* __restrict__ W_fc,
                            unsigned short* __restrict__ Bg,
                            float* __restrict__ bias,
                            unsigned short* __restrict__ Bin,
                            unsigned short* __restrict__ Bfc) {
    int idx = blockIdx.x * 256 + threadIdx.x;
    if (idx < NBGF) {
        int e    = idx & 7;
        int lane = (idx >> 3) & 63;
        int kk   = (idx >> 9) & 7;
        int nb   = (idx >> 12) & 15;
        int lg   = idx >> 16;          // 0..17
        int l = lg / 3, g = lg % 3;
        int f = nb * 16 + (lane & 15);
        int k = kk * 32 + (lane >> 4) * 8 + e;
        int r = f + (g == 0 ? 0 : (g == 1 ? 512 : 768));   // torch order i,f,g,o; f dead
        float sc = (g == 1) ? LOG2E2 : LOG2E;
        Bg[idx] = f2bf(W_ih[((size_t)l * 1024 + r) * HSZ + k] * sc);
        return;
    }
    idx -= NBGF;
    if (idx < NBIAS) {
        int j = idx % 768, l = idx / 768;
        int g = j >> 8;
        int r = (j < 256) ? j : j + 256;
        float sc = (g == 1) ? LOG2E2 : LOG2E;
        bias[idx] = (b_ih[l * 1024 + r] + b_hh[l * 1024 + r]) * sc;
        return;
    }
    idx -= NBIAS;
    if (idx < NBINF) {
        int e = idx & 7, lane = (idx >> 3) & 63, kk = (idx >> 9) & 1, nb = idx >> 10;
        int f = nb * 16 + (lane & 15);
        int k = kk * 32 + (lane >> 4) * 8 + e;
        Bin[idx] = (k < DIO) ? f2bf(W_in[f * DIO + k]) : (unsigned short)0;
        return;
    }
    idx -= NBINF;
    if (idx < NBFCF) {
        int e = idx & 7, lane = (idx >> 3) & 63, kk = (idx >> 9) & 7, nb = idx >> 12;
        int f = nb * 16 + (lane & 15);
        int k = kk * 32 + (lane >> 4) * 8 + e;
        Bfc[idx] = (f < DIO) ? f2bf(W_fc[f * HSZ + k]) : (unsigned short)0;
    }
}

// R3-shape: 8 waves, each owns ALL 64 steps (m=4) x 32 features (n=2) ->
// weight-redundancy-1 (1.18 GB L2/pass), 2 global loads : 16 MFMA per kk.
// h double-buffered [buf][kk=8][lq=4][s=64][e=8] -> 1 barrier/layer,
// conflict-light layout (R4/R6: 1.1M vs swizzled 3.3M).
__global__ __launch_bounds__(THREADS, 2) void rnn_fused(
    const float* __restrict__ inp, const float* __restrict__ b_in,
    const float* __restrict__ b_fc,
    const unsigned short* __restrict__ Bg, const float* __restrict__ bias,
    const unsigned short* __restrict__ Bin, const unsigned short* __restrict__ Bfc,
    float* __restrict__ out) {
    __shared__ __align__(16) unsigned short h_lds[2 * 8 * 4 * 64 * 8];   // 2 x 32KB
    __shared__ __align__(16) unsigned short in_lds[2 * 4 * 64 * 8];      // 8KB

    const int tid = threadIdx.x;
    const int lane = tid & 63;
    const int l15 = lane & 15;
    const int lq = lane >> 4;
    const int wid = tid >> 6;          // 0..7: features wid*32..+31, all 64 steps
    const int row0 = blockIdx.x * BM;

    // epilogue write position (feature f = wid*32+n*16+l15 -> kk'=wid):
    const int wrB = wid * 4096 + (l15 & 7) * 2;         // + ((n*2+(l15>>3))&3)*1024 + s*16
    const int lqw = (l15 >> 3);                          // feature bit3

    // ---- stage input tile (64 x 63 fp32 -> bf16, K pad 64), [kk=2][lq][s][e] ----
    for (int idx = tid; idx < BM * 64; idx += THREADS) {
        int s = idx >> 6, k = idx & 63;
        float v = (k < DIO) ? inp[(size_t)(row0 + s) * DIO + k] : 0.f;
        int off = (k >> 5) * 4096 + ((k >> 3) & 3) * 1024 + s * 16 + (k & 7) * 2;
        *(unsigned short*)((char*)in_lds + off) = f2bf(v);
    }
    __syncthreads();

    // ---- input GEMM: x = inp @ W_in^T + b_in -> h buf0 ----
    {
        f32x4 acc[4][2];
#pragma unroll
        for (int n = 0; n < 2; ++n) {
            float bn = b_in[wid * 32 + n * 16 + l15];
#pragma unroll
            for (int m = 0; m < 4; ++m) acc[m][n] = (f32x4){bn, bn, bn, bn};
        }
        const bf16_8* __restrict__ pB = (const bf16_8*)Bin;
#pragma unroll
        for (int kk = 0; kk < 2; ++kk) {
            bf16_8 a[4], b[2];
#pragma unroll
            for (int m = 0; m < 4; ++m)
                a[m] = *(const bf16_8*)((const char*)in_lds +
                        (kk * 4096 + lq * 1024 + (m * 16 + l15) * 16));
#pragma unroll
            for (int n = 0; n < 2; ++n) b[n] = pB[((wid * 2 + n) * 2 + kk) * 64 + lane];
#pragma unroll
            for (int m = 0; m < 4; ++m)
#pragma unroll
                for (int n = 0; n < 2; ++n)
                    acc[m][n] = __builtin_amdgcn_mfma_f32_16x16x32_bf16(a[m], b[n], acc[m][n], 0, 0, 0);
        }
#pragma unroll
        for (int m = 0; m < 4; ++m)
#pragma unroll
            for (int n = 0; n < 2; ++n) {
                int base = wrB + ((n * 2 + lqw) & 3) * 1024;
#pragma unroll
                for (int r = 0; r < 4; ++r)
                    *(unsigned short*)((char*)h_lds + base + (m * 16 + lq * 4 + r) * 16) =
                        f2bf(acc[m][n][r]);
            }
    }
    __syncthreads();

    // ---- 6 layers x 3 gates (i,g,o; f-gate dead: c_prev==0) ----
    for (int l = 0; l < NL; ++l) {
        const char* cur = (const char*)h_lds + (l & 1) * 32768;
        char* nxt = (char*)h_lds + ((l + 1) & 1) * 32768;
        f32x4 tt[4][2];
#pragma unroll
        for (int g = 0; g < 3; ++g) {
            const bf16_8* __restrict__ pB = (const bf16_8*)(Bg + ((size_t)(l * 3 + g) << 16));
            const float* __restrict__ bg = bias + (l * 3 + g) * 256;
            f32x4 acc[4][2];
#pragma unroll
            for (int n = 0; n < 2; ++n) {
                float bn = bg[wid * 32 + n * 16 + l15];
#pragma unroll
                for (int m = 0; m < 4; ++m) acc[m][n] = (f32x4){bn, bn, bn, bn};
            }
#pragma unroll
            for (int kk = 0; kk < 8; ++kk) {
                bf16_8 a[4], b[2];
#pragma unroll
                for (int n = 0; n < 2; ++n) b[n] = pB[((wid * 2 + n) * 8 + kk) * 64 + lane];
#pragma unroll
                for (int m = 0; m < 4; ++m)
                    a[m] = *(const bf16_8*)(cur + kk * 4096 + lq * 1024 + (m * 16 + l15) * 16);
#pragma unroll
                for (int m = 0; m < 4; ++m)
#pragma unroll
                    for (int n = 0; n < 2; ++n)
                        acc[m][n] = __builtin_amdgcn_mfma_f32_16x16x32_bf16(a[m], b[n], acc[m][n], 0, 0, 0);
            }
            // g0: tt = e^i;  g1: tt = c = ei(eg-1)/((1+ei)(1+eg))
            // g2: h = sig(o)*tanh(c) = (eo*c*tn(z)) / ((1+eo)*td(z)), z=c^2; write bf16
            if (g < 2) {
#pragma unroll
                for (int m = 0; m < 4; ++m)
#pragma unroll
                    for (int n = 0; n < 2; ++n)
#pragma unroll
                        for (int r = 0; r < 4; ++r) {
                            float v = acc[m][n][r];
                            if (g == 0) {
                                tt[m][n][r] = __builtin_amdgcn_exp2f(fminf(v, 34.f));
                            } else {
                                float eg = __builtin_amdgcn_exp2f(fminf(v, 60.f));
                                float ei = tt[m][n][r];
                                tt[m][n][r] = ei * (eg - 1.f) *
                                              __builtin_amdgcn_rcpf((1.f + ei) * (1.f + eg));
                            }
                        }
            } else {
#pragma unroll
                for (int m = 0; m < 4; ++m)
#pragma unroll
                    for (int n = 0; n < 2; ++n) {
                        int base = wrB + ((n * 2 + lqw) & 3) * 1024;
#pragma unroll
                        for (int r = 0; r < 4; ++r) {
                            float eo = __builtin_amdgcn_exp2f(fminf(acc[m][n][r], 34.f));
                            float c = tt[m][n][r];
                            float z = c * c;
                            float tn = fmaf(z + 105.f, z, 945.f);
                            float td = fmaf(fmaf(15.f, z, 420.f), z, 945.f);
                            *(unsigned short*)(nxt + base + (m * 16 + lq * 4 + r) * 16) =
                                f2bf(eo * c * tn * __builtin_amdgcn_rcpf((1.f + eo) * td));
                        }
                    }
            }
        }
        __syncthreads();   // nxt published; cur free
    }

    // ---- final GEMM: out = h @ W_fc^T + b_fc (h in buf0 since NL even) ----
    {
        const char* cur = (const char*)h_lds;
        const int fg = wid & 3;      // feature tile (16 cols)
        const int sg = wid >> 1 & 2; // step offset: wid 0-3 -> 0, 4-7 -> 2 (x16)
        // wave: steps (wid>>2)*32 .. +31 (m=2 tiles), feats fg*16..+15
        const int s0 = (wid >> 2) * 32;
        f32x4 o4[2];
#pragma unroll
        for (int m = 0; m < 2; ++m) o4[m] = (f32x4){0.f, 0.f, 0.f, 0.f};
        const bf16_8* __restrict__ pB = (const bf16_8*)Bfc;
#pragma unroll
        for (int kk = 0; kk < 8; ++kk) {
            bf16_8 b = pB[(fg * 8 + kk) * 64 + lane];
#pragma unroll
            for (int m = 0; m < 2; ++m) {
                bf16_8 a = *(const bf16_8*)(cur + kk * 4096 + lq * 1024 +
                                            (s0 + m * 16 + l15) * 16);
                o4[m] = __builtin_amdgcn_mfma_f32_16x16x32_bf16(a, b, o4[m], 0, 0, 0);
            }
        }
        int f = fg * 16 + l15;
        if (f < DIO) {
            float bn = b_fc[f];
#pragma unroll
            for (int m = 0; m < 2; ++m)
#pragma unroll
                for (int r = 0; r < 4; ++r) {
                    int s = row0 + s0 + m * 16 + lq * 4 + r;
                    out[(size_t)s * DIO + f] = o4[m][r] + bn;
                }
        }
        (void)sg;
    }
}

extern "C" void kernel_launch(void* const* d_in, const int* in_sizes, int n_in,
                              void* d_out, int out_size, void* d_ws, size_t ws_size,
                              hipStream_t stream) {
    const float* inputs = (const float*)d_in[0];
    const float* W_in   = (const float*)d_in[1];
    const float* b_in   = (const float*)d_in[2];
    const float* W_ih   = (const float*)d_in[3];
    // d_in[4] = W_hh: unused (h_prev == 0 every step)
    const float* b_ih   = (const float*)d_in[5];
    const float* b_hh   = (const float*)d_in[6];
    const float* W_fc   = (const float*)d_in[7];
    const float* b_fc   = (const float*)d_in[8];

    unsigned short* Bg  = (unsigned short*)d_ws;
    float* bias         = (float*)((char*)d_ws + (size_t)NBGF * 2);
    unsigned short* Bin = (unsigned short*)((char*)bias + (size_t)NBIAS * 4);
    unsigned short* Bfc = Bin + NBINF;

    int total = NBGF + NBIAS + NBINF + NBFCF;
    prep_kernel<<<(total + 255) / 256, 256, 0, stream>>>(W_in, W_ih, b_ih, b_hh, W_fc,
                                                         Bg, bias, Bin, Bfc);
    rnn_fused<<<STEPS / BM, THREADS, 0, stream>>>(inputs, b_in, b_fc, Bg, bias, Bin, Bfc,
                                                  (float*)d_out);
}

// Round 8
// 104.872 us; speedup vs baseline: 3.1694x; 1.6609x over previous
//
#include <hip/hip_runtime.h>

#define STEPS 32768
#define DIO 63
#define HSZ 256
#define NL 6
#define BM 64
#define THREADS 512

// Gate weights, A-role fragment order, grouped per (layer, pass, wave, kk) so one
// wave's 3 gate-fragments per kk are contiguous (3KB):
// Bg[(((((l*2+p)*8+wid)*8+kk)*3+g)*64 + lane)*8 + e], bf16, log2e-prescaled.
#define NBGF  (NL * 2 * 8 * 8 * 3 * 512)   // 1,179,648 bf16
#define NBIAS (NL * 768)                    // fused (b_ih+b_hh)*scale, f32, [l][g][256]
#define NBINF (16 * 2 * 64 * 8)             // W_in  [fb][kk][lane][e], K 63->64
#define NBFCF (4 * 8 * 64 * 8)              // W_fc  [fm][kk][lane][e]

typedef __bf16 bf16_8 __attribute__((ext_vector_type(8)));
typedef __bf16 bf16_4 __attribute__((ext_vector_type(4)));
typedef float f32x4 __attribute__((ext_vector_type(4)));

#define LOG2E  1.4426950408889634f
#define LOG2E2 2.8853900817779268f

__device__ __forceinline__ unsigned short f2bf(float f) {
    unsigned int u = __float_as_uint(f);
    u = u + 0x7fffu + ((u >> 16) & 1u);   // RNE
    return (unsigned short)(u >> 16);
}

__global__ void prep_kernel(const float* __restrict__ W_in,
                            const float* __restrict__ W_ih,
                            const float* __restrict__ b_ih,
                            const float* __restrict__ b_hh,
                            const float* __restrict__ W_fc,
                            unsigned short* __restrict__ Bg,
                            float* __restrict__ bias,
                            unsigned short* __restrict__ Bin,
                            unsigned short* __restrict__ Bfc) {
    int idx = blockIdx.x * 256 + threadIdx.x;
    if (idx < NBGF) {
        int e    = idx & 7;
        int lane = (idx >> 3) & 63;
        int t    = idx >> 9;       // (((l*2+p)*8+w)*8+kk)*3+g
        int g    = t % 3;
        int u    = t / 3;
        int kk   = u & 7;
        int v    = u >> 3;
        int w    = v & 7;
        int x    = v >> 3;
        int p    = x & 1;
        int l    = x >> 1;
        int f = (p * 8 + w) * 16 + (lane & 15);
        int k = kk * 32 + (lane >> 4) * 8 + e;
        int r = f + (g == 0 ? 0 : (g == 1 ? 512 : 768));   // torch order i,f,g,o; f dead
        float sc = (g == 1) ? LOG2E2 : LOG2E;
        Bg[idx] = f2bf(W_ih[((size_t)l * 1024 + r) * HSZ + k] * sc);
        return;
    }
    idx -= NBGF;
    if (idx < NBIAS) {
        int j = idx % 768, l = idx / 768;
        int g = j >> 8;
        int r = (j < 256) ? j : j + 256;
        float sc = (g == 1) ? LOG2E2 : LOG2E;
        bias[idx] = (b_ih[l * 1024 + r] + b_hh[l * 1024 + r]) * sc;
        return;
    }
    idx -= NBIAS;
    if (idx < NBINF) {
        int e = idx & 7, lane = (idx >> 3) & 63, kk = (idx >> 9) & 1, fb = idx >> 10;
        int f = fb * 16 + (lane & 15);
        int k = kk * 32 + (lane >> 4) * 8 + e;
        Bin[idx] = (k < DIO) ? f2bf(W_in[f * DIO + k]) : (unsigned short)0;
        return;
    }
    idx -= NBINF;
    if (idx < NBFCF) {
        int e = idx & 7, lane = (idx >> 3) & 63, kk = (idx >> 9) & 7, fm = idx >> 12;
        int f = fm * 16 + (lane & 15);
        int k = kk * 32 + (lane >> 4) * 8 + e;
        Bfc[idx] = (f < DIO) ? f2bf(W_fc[f * HSZ + k]) : (unsigned short)0;
    }
}

// v8: operand-swapped (A=W, B=h), all 3 gates accumulated CONCURRENTLY per pass
// (no act->GEMM serial chain inside a layer; one act phase per pass).
// 8 waves; per pass each wave owns 16 feats x 64 steps; 2 passes/layer, order
// staggered by wave parity so half the CU's waves MFMA while half activate.
// h double-buffered [buf][kk=8][lq=4][s=64][e=8]; 1 barrier/layer.
// Measured launch_bounds law: VGPR cap = 256/arg2 -> arg2=2 caps 128, demand ~105.
__global__ __launch_bounds__(THREADS, 2) void rnn_fused(
    const float* __restrict__ inp, const float* __restrict__ b_in,
    const float* __restrict__ b_fc,
    const unsigned short* __restrict__ Bg, const float* __restrict__ bias,
    const unsigned short* __restrict__ Bin, const unsigned short* __restrict__ Bfc,
    float* __restrict__ out) {
    __shared__ __align__(16) unsigned short h_lds[2 * 8 * 4 * 64 * 8];   // 2 x 32KB
    __shared__ __align__(16) unsigned short in_lds[2 * 4 * 64 * 8];      // 8KB

    const int tid = threadIdx.x;
    const int lane = tid & 63;
    const int l15 = lane & 15;
    const int lq = lane >> 4;
    const int wid = tid >> 6;
    const int row0 = blockIdx.x * BM;
    const int rdB = lq * 1024 + l15 * 16;   // one base for ALL B-role LDS reads

    // ---- stage input (64 x 63 fp32 -> bf16, K pad 64), layout [kk][lq][s][e] ----
    for (int idx = tid; idx < BM * 64; idx += THREADS) {
        int s = idx >> 6, k = idx & 63;
        float v = (k < DIO) ? inp[(size_t)(row0 + s) * DIO + k] : 0.f;
        int off = (k >> 5) * 4096 + ((k >> 3) & 3) * 1024 + s * 16 + (k & 7) * 2;
        *(unsigned short*)((char*)in_lds + off) = f2bf(v);
    }
    __syncthreads();

    // ---- input GEMM: x^T = W_in * inp^T + b_in -> h buf0 ----
    {
        f32x4 acc[2][4];
#pragma unroll
        for (int m = 0; m < 2; ++m) {
            f32x4 b4 = *(const f32x4*)(b_in + (2 * wid + m) * 16 + lq * 4);
#pragma unroll
            for (int n = 0; n < 4; ++n) acc[m][n] = b4;
        }
        const bf16_8* __restrict__ pA = (const bf16_8*)Bin + lane;
#pragma unroll
        for (int kk = 0; kk < 2; ++kk) {
            bf16_8 a[2], b[4];
#pragma unroll
            for (int m = 0; m < 2; ++m) a[m] = pA[((2 * wid + m) * 2 + kk) * 64];
#pragma unroll
            for (int n = 0; n < 4; ++n)
                b[n] = *(const bf16_8*)((const char*)in_lds + rdB + kk * 4096 + n * 256);
#pragma unroll
            for (int m = 0; m < 2; ++m)
#pragma unroll
                for (int n = 0; n < 4; ++n)
                    acc[m][n] = __builtin_amdgcn_mfma_f32_16x16x32_bf16(a[m], b[n], acc[m][n], 0, 0, 0);
        }
#pragma unroll
        for (int m = 0; m < 2; ++m) {
            int wb = wid * 4096 + (2 * m + (lq >> 1)) * 1024 + l15 * 16 + (lq & 1) * 8;
#pragma unroll
            for (int n = 0; n < 4; ++n) {
                bf16_4 hv;
#pragma unroll
                for (int r = 0; r < 4; ++r) hv[r] = (__bf16)acc[m][n][r];
                *(bf16_4*)((char*)h_lds + wb + n * 256) = hv;
            }
        }
    }
    __syncthreads();

    // ---- 6 layers; per layer: 2 passes x {3-gate concurrent GEMM, one act} ----
    for (int l = 0; l < NL; ++l) {
        const char* cur = (const char*)h_lds + (l & 1) * 32768;
        char* nxt = (char*)h_lds + ((l + 1) & 1) * 32768;
#pragma unroll
        for (int pi = 0; pi < 2; ++pi) {
            const int p = pi ^ (wid & 1);        // stagger pass order by wave parity
            const int fb = p * 8 + wid;          // feature block (16 feats)
            const float* bb = bias + l * 768 + fb * 16 + lq * 4;
            f32x4 ai[4], ag[4], ao[4];
            {
                f32x4 bi4 = *(const f32x4*)(bb);
                f32x4 bg4 = *(const f32x4*)(bb + 256);
                f32x4 bo4 = *(const f32x4*)(bb + 512);
#pragma unroll
                for (int n = 0; n < 4; ++n) { ai[n] = bi4; ag[n] = bg4; ao[n] = bo4; }
            }
            const bf16_8* __restrict__ pW =
                (const bf16_8*)Bg + (size_t)((l * 2 + p) * 8 + wid) * 1536 + lane;
#pragma unroll
            for (int kk = 0; kk < 8; ++kk) {
                bf16_8 wa = pW[kk * 192];
                bf16_8 wg = pW[kk * 192 + 64];
                bf16_8 wo = pW[kk * 192 + 128];
                bf16_8 b[4];
#pragma unroll
                for (int n = 0; n < 4; ++n)
                    b[n] = *(const bf16_8*)(cur + rdB + kk * 4096 + n * 256);
#pragma unroll
                for (int n = 0; n < 4; ++n) {
                    ai[n] = __builtin_amdgcn_mfma_f32_16x16x32_bf16(wa, b[n], ai[n], 0, 0, 0);
                    ag[n] = __builtin_amdgcn_mfma_f32_16x16x32_bf16(wg, b[n], ag[n], 0, 0, 0);
                    ao[n] = __builtin_amdgcn_mfma_f32_16x16x32_bf16(wo, b[n], ao[n], 0, 0, 0);
                }
            }
            // single act phase: c = sig(i)*tanh(g); h = sig(o)*tanh(c); packed b64 write
            const int wrp = (fb >> 1) * 4096 + ((fb & 1) * 2 + (lq >> 1)) * 1024 +
                            l15 * 16 + (lq & 1) * 8;
#pragma unroll
            for (int n = 0; n < 4; ++n) {
                bf16_4 hv;
#pragma unroll
                for (int r = 0; r < 4; ++r) {
                    float ei = __builtin_amdgcn_exp2f(fminf(ai[n][r], 34.f));
                    float eg = __builtin_amdgcn_exp2f(fminf(ag[n][r], 60.f));
                    float eo = __builtin_amdgcn_exp2f(fminf(ao[n][r], 34.f));
                    float c = ei * (eg - 1.f) *
                              __builtin_amdgcn_rcpf((1.f + ei) * (1.f + eg));
                    float z = c * c;
                    float tn = fmaf(z + 105.f, z, 945.f);
                    float td = fmaf(fmaf(15.f, z, 420.f), z, 945.f);
                    hv[r] = (__bf16)(eo * c * tn *
                                     __builtin_amdgcn_rcpf((1.f + eo) * td));
                }
                *(bf16_4*)(nxt + wrp + n * 256) = hv;
            }
        }
        __syncthreads();   // nxt published; cur free for overwrite next layer
    }

    // ---- final GEMM: out^T = W_fc * h^T + b_fc (h in buf0, NL even) ----
    {
        const char* cur = (const char*)h_lds;
        const int fm = wid & 3;             // feature frag (16 feats)
        const int sb = (wid >> 2) * 2;      // step frags sb, sb+1
        f32x4 o4[2];
#pragma unroll
        for (int n = 0; n < 2; ++n) o4[n] = (f32x4){0.f, 0.f, 0.f, 0.f};
        const bf16_8* __restrict__ pF = (const bf16_8*)Bfc + lane;
#pragma unroll
        for (int kk = 0; kk < 8; ++kk) {
            bf16_8 a = pF[(fm * 8 + kk) * 64];
#pragma unroll
            for (int n = 0; n < 2; ++n) {
                bf16_8 b = *(const bf16_8*)(cur + rdB + kk * 4096 + (sb + n) * 256);
                o4[n] = __builtin_amdgcn_mfma_f32_16x16x32_bf16(a, b, o4[n], 0, 0, 0);
            }
        }
#pragma unroll
        for (int n = 0; n < 2; ++n) {
            int s = row0 + (sb + n) * 16 + l15;
#pragma unroll
            for (int r = 0; r < 4; ++r) {
                int f = fm * 16 + lq * 4 + r;
                if (f < DIO) out[(size_t)s * DIO + f] = o4[n][r] + b_fc[f];
            }
        }
    }
}

extern "C" void kernel_launch(void* const* d_in, const int* in_sizes, int n_in,
                              void* d_out, int out_size, void* d_ws, size_t ws_size,
                              hipStream_t stream) {
    const float* inputs = (const float*)d_in[0];
    const float* W_in   = (const float*)d_in[1];
    const float* b_in   = (const float*)d_in[2];
    const float* W_ih   = (const float*)d_in[3];
    // d_in[4] = W_hh: unused (h_prev == 0 every step)
    const float* b_ih   = (const float*)d_in[5];
    const float* b_hh   = (const float*)d_in[6];
    const float* W_fc   = (const float*)d_in[7];
    const float* b_fc   = (const float*)d_in[8];

    unsigned short* Bg  = (unsigned short*)d_ws;
    float* bias         = (float*)((char*)d_ws + (size_t)NBGF * 2);
    unsigned short* Bin = (unsigned short*)((char*)bias + (size_t)NBIAS * 4);
    unsigned short* Bfc = Bin + NBINF;

    int total = NBGF + NBIAS + NBINF + NBFCF;
    prep_kernel<<<(total + 255) / 256, 256, 0, stream>>>(W_in, W_ih, b_ih, b_hh, W_fc,
                                                         Bg, bias, Bin, Bfc);
    rnn_fused<<<STEPS / BM, THREADS, 0, stream>>>(inputs, b_in, b_fc, Bg, bias, Bin, Bfc,
                                                  (float*)d_out);
}